// Round 20
// baseline (5790.391 us; speedup 1.0000x reference)
//
#include <hip/hip_runtime.h>

typedef _Float16 half8 __attribute__((ext_vector_type(8)));
typedef float f32x4 __attribute__((ext_vector_type(4)));

#define MFMA(a,b,c) __builtin_amdgcn_mfma_f32_16x16x32_f16((a),(b),(c),0,0,0)

// ---- workspace map (bytes) ----
// pkw: 16 col-streams (32 cols each): sid<4: 240 tiles (B192,D32,E16); sid>=4: 224 (B192,D32)
#define PKW_BYTES ((size_t)(4*240 + 12*224)*1024)       // 3,735,552
#define OFF_ETAB  PKW_BYTES                             // Etab f32: 131,072
#define OFF_H0    (OFF_ETAB + (size_t)64*512*4)         // h0 f32 2MB (aliased as exchange)
#define OFF_XPRE  (OFF_H0 + (size_t)1024*512*4)
#define OFF_HPRE  (OFF_XPRE + (size_t)1024*128*512*2)
#define OFF_FLG   (OFF_HPRE + (size_t)1024*128*512*2)   // 384 ints
// end = 274,400,768  (< proven ws floor 274,923,520)

__device__ __forceinline__ int ld_acq(const int* p){
  return __hip_atomic_load(p, __ATOMIC_ACQUIRE, __HIP_MEMORY_SCOPE_AGENT);
}
__device__ __forceinline__ void st_rel(int* p, int v){
  __hip_atomic_store(p, v, __ATOMIC_RELEASE, __HIP_MEMORY_SCOPE_AGENT);
}
__device__ __forceinline__ void spin_ge(const int* p, int v){
  int n = 0;
  while (ld_acq(p) < v && n < (1<<16)){ __builtin_amdgcn_s_sleep(8); n++; }
}

__device__ __forceinline__ long stream_base(int sid){  // tile index of stream base
  return (sid < 4) ? (long)sid*240 : (long)960 + (long)(sid-4)*224;
}

// ======= packw: 16 col-streams; stream sid owns cols sid*32..+31 =======
// ts<192: B: ts = i*96 + a*16 + kq (i<2; a<3: W_ih gate a; a>=3: W_hh gate a-3)
// ts in [192,224): D: i=(ts-192)>>4, ks=ts&15 (W_o1 top rows 0..511)
// sid<4: ts in [224,240): E: ks=ts-224 (W_o2, n = sid*16+lo)
__global__ void packw_k(const float* __restrict__ W_ih, const float* __restrict__ W_hh,
                        const float* __restrict__ W_o1, const float* __restrict__ W_o2,
                        _Float16* __restrict__ pkw)
{
  int ts = blockIdx.x, sid = blockIdx.y;
  if (sid >= 4 && ts >= 224) return;
  int lane = threadIdx.x, lo = lane & 15, kb8 = (lane >> 4)*8;
  half8 v;
  #pragma unroll
  for (int e = 0; e < 8; e++) v[e] = (_Float16)0.f;
  if (ts < 192){
    int i = ts/96, r = ts%96, a = r/16, kq = r%16;
    int n = sid*32 + i*16 + lo;
    #pragma unroll
    for (int e = 0; e < 8; e++){
      int k = kq*32 + kb8 + e;
      v[e] = (a < 3) ? (_Float16)W_ih[(a*512 + n)*512 + k]
                     : (_Float16)W_hh[((a-3)*512 + n)*512 + k];
    }
  } else if (ts < 224){
    int td = ts - 192;
    int i = td >> 4, ks = td & 15, n = sid*32 + i*16 + lo;
    #pragma unroll
    for (int e = 0; e < 8; e++) v[e] = (_Float16)W_o1[(ks*32 + kb8 + e)*512 + n];
  } else {
    int ks = ts - 224, n = sid*16 + lo;
    #pragma unroll
    for (int e = 0; e < 8; e++) v[e] = (_Float16)W_o2[(ks*32 + kb8 + e)*64 + n];
  }
  *(half8*)(pkw + (stream_base(sid) + ts)*512 + lane*8) = v;
}

// ---------------- flag init (each launch) ----------------
__global__ void flaginit_k(int* __restrict__ f){
  int i = threadIdx.x;
  if (i < 384) f[i] = 0;
}

// ---------------- Etab (f32) ----------------
__global__ void etab_k(const float* __restrict__ E, const float* __restrict__ W_in,
                       const float* __restrict__ b_in, float* __restrict__ Etab)
{
  int e = blockIdx.x, tid = threadIdx.x;
  __shared__ float er[256];
  if (tid < 256) er[tid] = E[e*256 + tid];
  __syncthreads();
  for (int j = tid; j < 512; j += 256){
    float acc = b_in[j];
    for (int k = 0; k < 256; k++) acc += er[k] * W_in[(256 + k)*512 + j];
    Etab[e*512 + j] = acc;
  }
}

// ---------------- h0 (f32) ----------------
__global__ __launch_bounds__(512) void h0_k(const float* __restrict__ ctx,
    const int* __restrict__ bh, const float* __restrict__ E,
    const float* __restrict__ W_init, const float* __restrict__ b_init,
    float* __restrict__ h0w)
{
  int b0 = blockIdx.x * 16, tid = threadIdx.x;
  __shared__ float cat[16][512];
  int c = tid & 255, rh = tid >> 8;
  for (int rr = 0; rr < 8; rr++){
    int r2 = rh*8 + rr;
    const float* p = ctx + ((b0 + r2)*128)*256 + c;
    float acc = 0.f;
    for (int t = 0; t < 128; t++) acc += p[t*256];
    cat[r2][c] = acc * (1.f/128.f);
    float s = 0.f;
    #pragma unroll
    for (int hh = 0; hh < 8; hh++){
      int e = bh[(b0 + r2)*8 + hh];
      s += E[e*256 + c];
    }
    cat[r2][256 + c] = s * 0.125f;
  }
  __syncthreads();
  int j = tid;
  float acc[16];
  #pragma unroll
  for (int r2 = 0; r2 < 16; r2++) acc[r2] = b_init[j];
  for (int k = 0; k < 512; k++){
    float wv = W_init[k*512 + j];
    #pragma unroll
    for (int r2 = 0; r2 < 16; r2++) acc[r2] += cat[r2][k] * wv;
  }
  #pragma unroll
  for (int r2 = 0; r2 < 16; r2++) h0w[(b0 + r2)*512 + j] = tanhf(acc[r2]);
}

// ---------------- prep: xpre = ctx@W_in_top, hpre = ctx@W_o1_bot (f16 out) ----------------
__global__ __launch_bounds__(512) void prep_k(const float* __restrict__ ctx,
    const float* __restrict__ W_in, const float* __restrict__ W_o1,
    _Float16* __restrict__ xpre, _Float16* __restrict__ hpre)
{
  int b = blockIdx.x, tid = threadIdx.x;
  int w = tid >> 6, lane = tid & 63, lo = lane & 15, hi = lane >> 4;
  extern __shared__ __align__(16) _Float16 A_lds[];

  {
    int ra = tid >> 2, ca = (tid & 3)*64;
    const float* p = ctx + ((long)b*128 + ra)*256 + ca;
    #pragma unroll
    for (int c8 = 0; c8 < 8; c8++){
      float4 f0 = *(const float4*)(p + c8*8);
      float4 f1 = *(const float4*)(p + c8*8 + 4);
      half8 v;
      v[0]=(_Float16)f0.x; v[1]=(_Float16)f0.y; v[2]=(_Float16)f0.z; v[3]=(_Float16)f0.w;
      v[4]=(_Float16)f1.x; v[5]=(_Float16)f1.y; v[6]=(_Float16)f1.z; v[7]=(_Float16)f1.w;
      *(half8*)((char*)A_lds + (((ra*512 + (ca + c8*8)*2)) ^ ((ra&7)<<4))) = v;
    }
  }
  __syncthreads();

  const float* Wb = (w < 4) ? W_in : (W_o1 + 512*512);
  _Float16* outp = (w < 4) ? xpre : hpre;
  const int colbase = (w & 3)*128;
  const int aswzp = (lo & 7) << 4;

  #pragma unroll 1
  for (int cth = 0; cth < 4; cth++){
    half8 bf0[8], bf1[8];
    const int n0 = colbase + cth*32 + lo;
    #pragma unroll
    for (int ks = 0; ks < 8; ks++){
      const int kb = ks*32 + hi*8;
      half8 v0, v1;
      #pragma unroll
      for (int e = 0; e < 8; e++){
        v0[e] = (_Float16)Wb[(kb + e)*512 + n0];
        v1[e] = (_Float16)Wb[(kb + e)*512 + n0 + 16];
      }
      bf0[ks] = v0; bf1[ks] = v1;
    }
    #pragma unroll 1
    for (int rt = 0; rt < 8; rt++){
      f32x4 acc0 = {0,0,0,0}, acc1 = {0,0,0,0};
      #pragma unroll
      for (int ks = 0; ks < 8; ks++){
        half8 a = *(const half8*)((const char*)A_lds +
                   ((((rt*16 + lo)*512 + hi*16 + ks*64)) ^ aswzp));
        acc0 = MFMA(a, bf0[ks], acc0);
        acc1 = MFMA(a, bf1[ks], acc1);
      }
      #pragma unroll
      for (int rr = 0; rr < 4; rr++){
        int t = rt*16 + hi*4 + rr;
        long rowoff = ((long)b*128 + t)*512 + colbase + cth*32;
        outp[rowoff +      lo] = (_Float16)acc0[rr];
        outp[rowoff + 16 + lo] = (_Float16)acc1[rr];
      }
    }
  }
}

// ====== main: 128 WGs x 512 thr; group g=bid>>1 (16 rows), slice s=bid&1 (256 cols) ======
#define AFRAG(buf, base, ks) (*(const half8*)((const char*)(buf) + ((((base) + (ks)*64)) ^ aswz)))
#define WSTORE(buf, row, j, val) \
  *(_Float16*)((char*)(buf) + ((((row)*1024 + (j)*2)) ^ ((((row)&7))<<4))) = (_Float16)(val)
#define WSTORE8(buf, row, colf16, v8) \
  *(half8*)((char*)(buf) + ((((row)*1024 + (colf16)*2)) ^ ((((row)&7))<<4))) = (v8)

__global__ __launch_bounds__(512) void main12_k(
    const _Float16* __restrict__ pkw, const float* __restrict__ Etab,
    float* __restrict__ h0w, const _Float16* __restrict__ xpre,
    const _Float16* __restrict__ hpre, const int* __restrict__ bh,
    const float* __restrict__ b_ih, const float* __restrict__ b_hh,
    const float* __restrict__ lng, const float* __restrict__ lnb,
    const float* __restrict__ b_o1, const float* __restrict__ b_o2,
    int* __restrict__ flags, float* __restrict__ out)
{
  const int bid = blockIdx.x, tid = threadIdx.x;
  const int g = bid >> 1, s = bid & 1, peer = s ^ 1;
  const int w = tid >> 6, lane = tid & 63, lo = lane & 15, hi = lane >> 4;
  const int r0 = g*16, sid = s*8 + w;

  __shared__ __align__(16) _Float16 hbuf[16*512];   // h(t-1)/h(t) full, f16 swz
  __shared__ __align__(16) _Float16 hn_s[16*512];
  __shared__ __align__(16) _Float16 xh_s[16*512];   // x, then hidden
  __shared__ float lg_s[16*64];
  __shared__ float stats[8][4][4][2];
  __shared__ float murs[16][2];
  __shared__ float bias_s[3*512];                   // b_o1, ln_g, ln_b
  __shared__ int   pb[16];

  char* regi  = (char*)h0w + (long)g*32768;
  char* hx_own  = regi + s*8192;
  char* hx_peer = regi + peer*8192;
  float* ps_own  = (float*)(regi + 16384 + s*128);
  float* ps_peer = (float*)(regi + 16384 + peer*128);
  int* flag_p = flags;
  int* flag_h = flags + 128;
  int* ackf   = flags + 256;

  float bcr[2], bcz[2], bin_[2], bhn[2];
  #pragma unroll
  for (int i = 0; i < 2; i++){
    int j = sid*32 + i*16 + lo;
    bcr[i] = b_ih[j]     + b_hh[j];
    bcz[i] = b_ih[512+j] + b_hh[512+j];
    bin_[i]= b_ih[1024+j];
    bhn[i] = b_hh[1024+j];
  }
  const float bo2v = (w < 4) ? b_o2[w*16 + lo] : 0.f;
  bias_s[tid]        = b_o1[tid];
  bias_s[512 + tid]  = lng[tid];
  bias_s[1024 + tid] = lnb[tid];

  float hreg[2][4];
  #pragma unroll
  for (int i = 0; i < 2; i++)
    #pragma unroll
    for (int rr = 0; rr < 4; rr++)
      hreg[i][rr] = h0w[(r0 + hi*4 + rr)*512 + sid*32 + i*16 + lo];

  {
    int rr = tid >> 5, c16 = (tid & 31)*16;
    const float* p = h0w + (r0 + rr)*512 + c16;
    half8 v0, v1;
    #pragma unroll
    for (int e = 0; e < 8; e++){ v0[e] = (_Float16)p[e]; v1[e] = (_Float16)p[8+e]; }
    WSTORE8(hbuf, rr, c16,     v0);
    WSTORE8(hbuf, rr, c16 + 8, v1);
  }
  if (tid < 16) pb[tid] = bh[(r0 + tid)*8 + 7];
  __syncthreads();

  if (tid == 0){
    __threadfence();
    st_rel(&flag_p[g*2 + s], 1);
    spin_ge(&flag_p[g*2 + peer], 1);
  }
  __syncthreads();

  const int aswz  = (lo & 7) << 4;
  const int abase = lo*1024 + hi*16;
  const char* pkb = (const char*)pkw;
  const char* pkw_w = pkb + (stream_base(sid) << 10);

  #pragma unroll 1
  for (int t = 0; t < 128; t++){
    // ---- A: x = relu(xpre + Etab[pb]) -> xh_s (full 512 cols) ----
    {
      int rowA = tid >> 5, c32 = (tid & 31)*16;
      const _Float16* xp = xpre + (((long)(r0 + rowA)*128 + t)*512) + c32;
      half8 x0 = __builtin_nontemporal_load((const half8*)xp);
      half8 x1 = __builtin_nontemporal_load((const half8*)(xp + 8));
      const float* ep = Etab + pb[rowA]*512 + c32;
      float4 e0 = *(const float4*)(ep);
      float4 e1 = *(const float4*)(ep + 4);
      float4 e2 = *(const float4*)(ep + 8);
      float4 e3 = *(const float4*)(ep + 12);
      half8 o0, o1;
      o0[0]=(_Float16)fmaxf((float)x0[0]+e0.x,0.f); o0[1]=(_Float16)fmaxf((float)x0[1]+e0.y,0.f);
      o0[2]=(_Float16)fmaxf((float)x0[2]+e0.z,0.f); o0[3]=(_Float16)fmaxf((float)x0[3]+e0.w,0.f);
      o0[4]=(_Float16)fmaxf((float)x0[4]+e1.x,0.f); o0[5]=(_Float16)fmaxf((float)x0[5]+e1.y,0.f);
      o0[6]=(_Float16)fmaxf((float)x0[6]+e1.z,0.f); o0[7]=(_Float16)fmaxf((float)x0[7]+e1.w,0.f);
      o1[0]=(_Float16)fmaxf((float)x1[0]+e2.x,0.f); o1[1]=(_Float16)fmaxf((float)x1[1]+e2.y,0.f);
      o1[2]=(_Float16)fmaxf((float)x1[2]+e2.z,0.f); o1[3]=(_Float16)fmaxf((float)x1[3]+e2.w,0.f);
      o1[4]=(_Float16)fmaxf((float)x1[4]+e3.x,0.f); o1[5]=(_Float16)fmaxf((float)x1[5]+e3.y,0.f);
      o1[6]=(_Float16)fmaxf((float)x1[6]+e3.z,0.f); o1[7]=(_Float16)fmaxf((float)x1[7]+e3.w,0.f);
      WSTORE8(xh_s, rowA, c32,     o0);
      WSTORE8(xh_s, rowA, c32 + 8, o1);
    }
    __syncthreads();

    // ---- B: gates (slice-local cols, reg path), i<2 per wave ----
    float srow[4] = {0,0,0,0}, sqrow[4] = {0,0,0,0};
    #pragma unroll 1
    for (int i = 0; i < 2; i++){
      f32x4 a0={0,0,0,0},a1={0,0,0,0},a2={0,0,0,0},a3={0,0,0,0},a4={0,0,0,0},a5={0,0,0,0};
      #pragma unroll
      for (int a6 = 0; a6 < 6; a6++){
        const _Float16* ab = (a6 < 3) ? xh_s : hbuf;
        #pragma unroll
        for (int hf = 0; hf < 2; hf++){
          half8 bb[8];
          const char* tp = pkw_w + (((long)(i*96 + a6*16 + hf*8)) << 10) + (lane << 4);
          #pragma unroll
          for (int k8 = 0; k8 < 8; k8++)
            bb[k8] = *(const half8*)(tp + ((long)k8 << 10));
          #pragma unroll
          for (int k8 = 0; k8 < 8; k8++){
            half8 af = AFRAG(ab, abase, hf*8 + k8);
            if      (a6 == 0) a0 = MFMA(af, bb[k8], a0);
            else if (a6 == 1) a1 = MFMA(af, bb[k8], a1);
            else if (a6 == 2) a2 = MFMA(af, bb[k8], a2);
            else if (a6 == 3) a3 = MFMA(af, bb[k8], a3);
            else if (a6 == 4) a4 = MFMA(af, bb[k8], a4);
            else              a5 = MFMA(af, bb[k8], a5);
          }
        }
      }
      #pragma unroll
      for (int rr = 0; rr < 4; rr++){
        float rg = 1.f/(1.f + __expf(-(a0[rr] + a3[rr] + bcr[i])));
        float zg = 1.f/(1.f + __expf(-(a1[rr] + a4[rr] + bcz[i])));
        float aa = (a2[rr] + bin_[i]) + rg*(a5[rr] + bhn[i]);
        float ea = __expf(-2.f*fabsf(aa));
        float th = (1.f - ea)/(1.f + ea);
        float ng = (aa < 0.f) ? -th : th;
        float hv = (1.f - zg)*ng + zg*hreg[i][rr];
        hreg[i][rr] = hv;
        srow[rr] += hv; sqrow[rr] += hv*hv;
      }
    }
    #pragma unroll
    for (int d = 1; d < 16; d <<= 1){
      #pragma unroll
      for (int rr = 0; rr < 4; rr++){
        srow[rr]  += __shfl_xor(srow[rr],  d);
        sqrow[rr] += __shfl_xor(sqrow[rr], d);
      }
    }
    if (lo == 0){
      #pragma unroll
      for (int rr = 0; rr < 4; rr++){
        stats[w][hi][rr][0] = srow[rr];
        stats[w][hi][rr][1] = sqrow[rr];
      }
    }
    __syncthreads();

    // ---- C: exchange h slice + LN stats; build hbuf full + hn_s full ----
    #pragma unroll
    for (int rr = 0; rr < 4; rr++){
      int row = hi*4 + rr;
      #pragma unroll
      for (int i = 0; i < 2; i++)
        WSTORE(hbuf, row, sid*32 + i*16 + lo, hreg[i][rr]);
    }
    __syncthreads();
    if (tid == 0) spin_ge(&ackf[g*2 + peer], t);
    __syncthreads();
    {
      int row = tid >> 5, k = tid & 31;
      half8 v = *(const half8*)((const char*)hbuf + row*1024 + s*512 + k*16);
      *(half8*)(hx_own + row*512 + k*16) = v;
      if (w == 0 && lane < 16){
        float sv = 0.f, qv = 0.f;
        #pragma unroll
        for (int ww = 0; ww < 8; ww++){
          sv += stats[ww][lane>>2][lane&3][0];
          qv += stats[ww][lane>>2][lane&3][1];
        }
        ps_own[lane*2 + 0] = sv;
        ps_own[lane*2 + 1] = qv;
      }
    }
    __syncthreads();
    if (tid == 0){
      __threadfence();
      st_rel(&flag_h[g*2 + s], t + 1);
      spin_ge(&flag_h[g*2 + peer], t + 1);
    }
    __syncthreads();
    {
      int row = tid >> 5, k = tid & 31;
      half8 v = *(const half8*)(hx_peer + row*512 + k*16);
      *(half8*)((char*)hbuf + row*1024 + peer*512 + k*16) = v;
      if (w == 0 && lane < 16){
        float sv = 0.f, qv = 0.f;
        #pragma unroll
        for (int ww = 0; ww < 8; ww++){
          sv += stats[ww][lane>>2][lane&3][0];
          qv += stats[ww][lane>>2][lane&3][1];
        }
        float sp = ps_peer[lane*2 + 0];
        float qp = ps_peer[lane*2 + 1];
        float su = sv + sp, qu = qv + qp;
        float mu = su*(1.f/512.f);
        float var = qu*(1.f/512.f) - mu*mu;
        murs[lane][0] = mu;
        murs[lane][1] = rsqrtf(var + 1e-5f);
      }
    }
    __syncthreads();
    if (tid == 0){ __threadfence(); st_rel(&ackf[g*2 + s], t + 1); }
    // c7: hn full from f16 hbuf (FIX: per-chunk swizzle on BOTH 16B reads)
    float hp[4][4];
    {
      int row = tid >> 5, c16 = (tid & 31)*16;
      float mu = murs[row][0], rs = murs[row][1];
      const int swz = (row & 7) << 4;
      const int base = row*1024 + c16*2;
      half8 v0 = *(const half8*)((const char*)hbuf + ((base     ) ^ swz));
      half8 v1 = *(const half8*)((const char*)hbuf + ((base + 16) ^ swz));
      half8 o0, o1;
      #pragma unroll
      for (int e = 0; e < 8; e++){
        o0[e] = (_Float16)(((float)v0[e] - mu)*rs*bias_s[512 + c16 + e]     + bias_s[1024 + c16 + e]);
        o1[e] = (_Float16)(((float)v1[e] - mu)*rs*bias_s[512 + c16 + 8 + e] + bias_s[1024 + c16 + 8 + e]);
      }
      WSTORE8(hn_s, row, c16,     o0);
      WSTORE8(hn_s, row, c16 + 8, o1);
    }
    #pragma unroll
    for (int rr = 0; rr < 4; rr++){
      int row = hi*4 + rr;
      #pragma unroll
      for (int i = 0; i < 4; i++)
        hp[i][rr] = (float)__builtin_nontemporal_load(
            &hpre[(((long)(r0 + row)*128 + t)*512) + w*64 + i*16 + lo]);
    }
    __syncthreads();

    // ---- D (full width, duplicated): hidden = relu(hn @ W_o1top + hpre + b_o1) ----
    #pragma unroll 1
    for (int i = 0; i < 4; i++){
      const int nt = w*4 + i;
      const int sd = nt >> 1, id = nt & 1;
      const char* dp = pkb + ((stream_base(sd) + 192 + id*16) << 10) + (lane << 4);
      half8 bd[16];
      #pragma unroll
      for (int ks = 0; ks < 16; ks++)
        bd[ks] = *(const half8*)(dp + ((long)ks << 10));
      f32x4 dacc = {0,0,0,0};
      #pragma unroll
      for (int ks = 0; ks < 16; ks++)
        dacc = MFMA(AFRAG(hn_s, abase, ks), bd[ks], dacc);
      const float bo1j = bias_s[w*64 + i*16 + lo];
      #pragma unroll
      for (int rr = 0; rr < 4; rr++){
        int row = hi*4 + rr;
        WSTORE(xh_s, row, w*64 + i*16 + lo, fmaxf(dacc[rr] + bo1j + hp[i][rr], 0.f));
      }
    }
    __syncthreads();

    // ---- E (full, duplicated): logits = hidden @ W_o2 + b_o2 (waves 0-3) ----
    if (w < 4){
      const char* ep_ = pkb + (((long)w*240 + 224) << 10) + (lane << 4);
      half8 be[16];
      #pragma unroll
      for (int ks = 0; ks < 16; ks++)
        be[ks] = *(const half8*)(ep_ + ((long)ks << 10));
      f32x4 eacc = {0,0,0,0};
      #pragma unroll
      for (int ks = 0; ks < 16; ks++)
        eacc = MFMA(AFRAG(xh_s, abase, ks), be[ks], eacc);
      #pragma unroll
      for (int rr = 0; rr < 4; rr++){
        int row = hi*4 + rr;
        lg_s[row*64 + w*16 + lo] = eacc[rr] + bo2v;
      }
    }
    __syncthreads();

    // ---- F: out store (slice 0 only) + argmax (identical both slices) ----
    #pragma unroll
    for (int sub = 0; sub < 2; sub++){
      int r2 = w*2 + sub;
      float v = lg_s[r2*64 + lane];
      if (s == 0)
        __builtin_nontemporal_store(v, &out[(((long)(r0 + r2))*128 + t)*64 + lane]);
      int idx = lane;
      #pragma unroll
      for (int d = 1; d < 64; d <<= 1){
        float ov = __shfl_xor(v, d);
        int oi = __shfl_xor(idx, d);
        if (ov > v || (ov == v && oi < idx)){ v = ov; idx = oi; }
      }
      if (lane == 0) pb[r2] = idx;
    }
    __syncthreads();
  }
}

extern "C" void kernel_launch(void* const* d_in, const int* in_sizes, int n_in,
                              void* d_out, int out_size, void* d_ws, size_t ws_size,
                              hipStream_t stream)
{
  const float* ctx    = (const float*)d_in[0];
  const int*   bh     = (const int*)d_in[1];
  const float* E      = (const float*)d_in[2];
  const float* W_in   = (const float*)d_in[3];
  const float* b_in   = (const float*)d_in[4];
  const float* W_init = (const float*)d_in[5];
  const float* b_init = (const float*)d_in[6];
  const float* W_ih   = (const float*)d_in[7];
  const float* W_hh   = (const float*)d_in[8];
  const float* b_ih   = (const float*)d_in[9];
  const float* b_hh   = (const float*)d_in[10];
  const float* ln_g   = (const float*)d_in[11];
  const float* ln_b   = (const float*)d_in[12];
  const float* W_o1   = (const float*)d_in[13];
  const float* b_o1   = (const float*)d_in[14];
  const float* W_o2   = (const float*)d_in[15];
  const float* b_o2   = (const float*)d_in[16];
  float* out = (float*)d_out;

  _Float16* pkw  = (_Float16*)d_ws;
  float*    Etab = (float*)((char*)d_ws + OFF_ETAB);
  float*    h0w  = (float*)((char*)d_ws + OFF_H0);
  _Float16* xpre = (_Float16*)((char*)d_ws + OFF_XPRE);
  _Float16* hpre = (_Float16*)((char*)d_ws + OFF_HPRE);
  int*      flg  = (int*)((char*)d_ws + OFF_FLG);

  (void)hipFuncSetAttribute((const void*)prep_k,
      hipFuncAttributeMaxDynamicSharedMemorySize, 65536);

  hipLaunchKernelGGL(packw_k, dim3(240, 16), dim3(64), 0, stream, W_ih, W_hh, W_o1, W_o2, pkw);
  hipLaunchKernelGGL(flaginit_k, dim3(1), dim3(384), 0, stream, flg);
  hipLaunchKernelGGL(etab_k, dim3(64), dim3(256), 0, stream, E, W_in, b_in, Etab);
  hipLaunchKernelGGL(h0_k, dim3(64), dim3(512), 0, stream, ctx, bh, E, W_init, b_init, h0w);
  hipLaunchKernelGGL(prep_k, dim3(1024), dim3(512), 65536, stream, ctx, W_in, W_o1, xpre, hpre);
  hipLaunchKernelGGL(main12_k, dim3(128), dim3(512), 0, stream,
                     pkw, Etab, h0w, xpre, hpre, bh,
                     b_ih, b_hh, ln_g, ln_b, b_o1, b_o2, flg, out);
}